// Round 11
// baseline (70.352 us; speedup 1.0000x reference)
//
#include <hip/hip_runtime.h>
#include <hip/hip_bf16.h>

#define LL 128
#define DD 256
#define PP 1024
#define TU_C 86400
#define TB_C 3600
#define NEGF -4294967296.0f   // float(-2**32+1) rounds to -2^32

// NOTE: parameter names must not collide with .x/.y/.z/.w member tokens
#define FMA4(ACC_, SS_, WW_) { (ACC_).x += (SS_)*(WW_).x; (ACC_).y += (SS_)*(WW_).y; (ACC_).z += (SS_)*(WW_).z; (ACC_).w += (SS_)*(WW_).w; }
#define ADD4(ACC_, WW_) { (ACC_).x += (WW_).x; (ACC_).y += (WW_).y; (ACC_).z += (WW_).z; (ACC_).w += (WW_).w; }

__device__ __forceinline__ float wredSum(float v) {
#pragma unroll
  for (int o = 32; o; o >>= 1) v += __shfl_xor(v, o);
  return v;
}
__device__ __forceinline__ float wredMax(float v) {
#pragma unroll
  for (int o = 32; o; o >>= 1) v = fmaxf(v, __shfl_xor(v, o));
  return v;
}

// ---------------------------------------------------------------------------
// Kernel 0: transpose weights. WT: WTq 0, WTk 65536, WTv 131072, WTf1 196608,
// WTf2 262144, WTdec 327680. 32x32 tiles, 576 blocks. (proven)
// ---------------------------------------------------------------------------
__global__ __launch_bounds__(256) void k_wt(
    const float* __restrict__ wq, const float* __restrict__ wk,
    const float* __restrict__ wv, const float* __restrict__ wf1,
    const float* __restrict__ wf2, const float* __restrict__ wdec,
    float* __restrict__ wt)
{
  __shared__ float s[32][33];
  const int tile = blockIdx.x;
  const float* src; float* dst; int R, m;
  if (tile < 320) {
    const int mi = tile >> 6; m = tile & 63;
    src = (mi == 0) ? wq : (mi == 1) ? wk : (mi == 2) ? wv : (mi == 3) ? wf1 : wf2;
    dst = wt + mi * 65536; R = 256;
  } else {
    m = tile - 320; src = wdec; dst = wt + 327680; R = 1024;
  }
  const int sr = (m >> 3) * 32, sc0 = (m & 7) * 32;
  const int tx = threadIdx.x & 31, ty = threadIdx.x >> 5;
#pragma unroll
  for (int i = 0; i < 4; ++i)
    s[ty + 8 * i][tx] = src[(sr + ty + 8 * i) * 256 + sc0 + tx];
  __syncthreads();
#pragma unroll
  for (int i = 0; i < 4; ++i)
    dst[(sc0 + ty + 8 * i) * R + sr + tx] = s[tx][ty + 8 * i];
}

// ---------------------------------------------------------------------------
// Kernel 1: Q/K/V projections. grid (64,3), 512 thr. (proven)
// K written TRANSPOSED per batch: KT[b][e][k].
// ---------------------------------------------------------------------------
__global__ __launch_bounds__(512) void k_qkv(
    const float* __restrict__ src, const float* __restrict__ wt,
    const float* __restrict__ bq, const float* __restrict__ bk,
    const float* __restrict__ bv,
    float* __restrict__ Q, float* __restrict__ KT, float* __restrict__ V)
{
  __shared__ float xs[8][DD];
  const int t = threadIdx.x, cg = t & 63, rg = t >> 6;
  const int r0 = blockIdx.x * 8;
  const int mat = blockIdx.y;
  const float* w = wt + mat * 65536;
  const float* bi = (mat == 0) ? bq : (mat == 1) ? bk : bv;
  for (int i = t; i < 8 * DD; i += 512) xs[i >> 8][i & 255] = src[r0 * DD + i];
  __syncthreads();
  float4 a0 = *(const float4*)(bi + 4 * cg);
  float4 a1 = {0.f,0.f,0.f,0.f}, a2 = {0.f,0.f,0.f,0.f}, a3 = {0.f,0.f,0.f,0.f};
  for (int e = 0; e < DD; e += 4) {
    const float4 xa = *(const float4*)&xs[rg][e];
    const float* wp = w + e * DD + 4 * cg;
    FMA4(a0, xa.x, *(const float4*)(wp))
    FMA4(a1, xa.y, *(const float4*)(wp + DD))
    FMA4(a2, xa.z, *(const float4*)(wp + 2 * DD))
    FMA4(a3, xa.w, *(const float4*)(wp + 3 * DD))
  }
  a0.x = (a0.x + a1.x) + (a2.x + a3.x);
  a0.y = (a0.y + a1.y) + (a2.y + a3.y);
  a0.z = (a0.z + a1.z) + (a2.z + a3.z);
  a0.w = (a0.w + a1.w) + (a2.w + a3.w);
  const int r = r0 + rg;
  if (mat == 1) {
    const int bA = r >> 7, kA = r & 127;
    KT[bA * 32768 + (4 * cg + 0) * 128 + kA] = a0.x;
    KT[bA * 32768 + (4 * cg + 1) * 128 + kA] = a0.y;
    KT[bA * 32768 + (4 * cg + 2) * 128 + kA] = a0.z;
    KT[bA * 32768 + (4 * cg + 3) * 128 + kA] = a0.w;
  } else {
    float* o = (mat == 0) ? Q : V;
    *(float4*)(o + r * DD + 4 * cg) = a0;
  }
}

// ---------------------------------------------------------------------------
// Kernel 2: FULLY FUSED attention + FFN. grid 256 = (b, 64 row-pairs),
// 512 thr = 8 waves. Scores: waves 0-3 = (row, k-half) K-dots, waves 4-5 =
// emb dots. Softmax cross-wave via LDS red. Then 3-phase FFN pipeline
// (round-10 proven): every reduction split over 8 waves, both rows share
// each weight/V line.
// ---------------------------------------------------------------------------
__global__ __launch_bounds__(512) void k_attn(
    const float* __restrict__ Q, const float* __restrict__ KT,
    const float* __restrict__ Vm, const float* __restrict__ src,
    const float* __restrict__ hour_emb, const float* __restrict__ day_emb,
    const int* __restrict__ seq_lens, const int* __restrict__ ts_g,
    const float* __restrict__ g11, const float* __restrict__ b11,
    const float* __restrict__ wt1, const float* __restrict__ bf1,
    const float* __restrict__ wt2, const float* __restrict__ bf2,
    const float* __restrict__ g12, const float* __restrict__ b12,
    float* __restrict__ F)
{
  const int b = blockIdx.x >> 6;
  const int j0 = (blockIdx.x & 63) * 2;
  const int t = threadIdx.x, w = t >> 6, l = t & 63;
  const int col = 4 * l;
  __shared__ float qs[2][DD];
  __shared__ int   tsl[LL];
  __shared__ float qhd[2][34];
  __shared__ float whd[2][34];
  __shared__ float red[8];
  __shared__ float ss[2][LL];
  __shared__ float xs2[2][DD];
  __shared__ float hs2[2][DD];
  __shared__ float ps[8][2][DD];
  const int row0 = b * LL + j0;
  qs[t >> 8][t & 255] = Q[row0 * DD + t];    // 512 threads = 2x256
  if (t < LL) tsl[t] = ts_g[b * LL + t];
  if (t < 68) whd[t / 34][t % 34] = 0.f;
  __syncthreads();   // B1
  // ---- K-dots (waves 0-3) and emb dots (waves 4-5) in parallel ----
  float kdot = 0.f;
  int krow = 0, kidx = 0;
  if (w < 4) {
    krow = w >> 1;
    kidx = ((w & 1) << 6) | l;
    const float* ktb = KT + b * 32768;
    float4 kd = {0.f,0.f,0.f,0.f};
#pragma unroll 8
    for (int e = 0; e < DD; e += 4) {
      const float4 q4 = *(const float4*)&qs[krow][e];
      const float* kp = ktb + e * LL + kidx;
      kd.x += q4.x * kp[0];
      kd.y += q4.y * kp[128];
      kd.z += q4.z * kp[256];
      kd.w += q4.w * kp[384];
    }
    kdot = (kd.x + kd.y) + (kd.z + kd.w);
  } else if (w < 6 && l < 34) {
    const int r = w - 4;
    const float* ep = (l < 26) ? (hour_emb + l * DD) : (day_emb + (l - 26) * DD);
    float4 ed = {0.f,0.f,0.f,0.f};
    for (int e = 0; e < DD; e += 4) {
      const float4 q4 = *(const float4*)&qs[r][e];
      const float4 e4 = *(const float4*)(ep + e);
      ed.x += q4.x * e4.x; ed.y += q4.y * e4.y;
      ed.z += q4.z * e4.z; ed.w += q4.w * e4.w;
    }
    qhd[r][l] = (ed.x + ed.y) + (ed.z + ed.w);
  }
  __syncthreads();   // B2 (qhd ready)
  // ---- scores + cross-wave softmax ----
  const int len = seq_lens[b];
  float s = NEGF;
  int hidx = 0, didx = 0;
  if (w < 4) {
    const int jrow = j0 + krow;
    if (kidx <= jrow && jrow < len) {
      const int df = tsl[jrow] - tsl[kidx];              // >=0 (sorted, k<=j)
      hidx = (jrow == b) ? 1 : ((df % TU_C) / TB_C + 2); // faithful j==b bug
      didx = min(df / TU_C + 1, 7);
      s = (kdot + qhd[krow][hidx] + qhd[krow][26 + didx]) * 0.0625f;
    }
    const float mv = wredMax(s);
    if (l == 0) red[w] = mv;
  }
  __syncthreads();   // B3
  float p = 0.f;
  if (w < 4) {
    const float m = fmaxf(red[2 * krow], red[2 * krow + 1]);
    p = expf(s - m);                 // all-NEG row -> p=1 everywhere
    const float sv = wredSum(p);
    if (l == 0) red[4 + w] = sv;
  }
  __syncthreads();   // B4
  if (w < 4) {
    const float Z = red[4 + 2 * krow] + red[5 + 2 * krow];
    const float aw = p / Z;          // all-NEG row -> uniform 1/128
    ss[krow][kidx] = aw;
    atomicAdd(&whd[krow][hidx], aw);       // idx 0 -> zero emb row: harmless
    atomicAdd(&whd[krow][26 + didx], aw);
  }
  __syncthreads();   // B5
  // ---- Phase 1: aw@V k-slice (16 k's per wave), both rows ----
  {
    float4 a0 = {0.f,0.f,0.f,0.f}, a1 = {0.f,0.f,0.f,0.f};
    const float* vb = Vm + b * LL * DD + col;
    const int k0 = 16 * w;
#pragma unroll
    for (int kk = 0; kk < 16; ++kk) {
      const int k = k0 + kk;
      const float4 v4 = *(const float4*)(vb + k * DD);
      FMA4(a0, ss[0][k], v4)
      FMA4(a1, ss[1][k], v4)
    }
    if (w == 0) {
#pragma unroll
      for (int i = 0; i < 26; ++i)
        FMA4(a0, whd[0][i], *(const float4*)(hour_emb + i * DD + col))
    } else if (w == 1) {
#pragma unroll
      for (int i = 0; i < 26; ++i)
        FMA4(a1, whd[1][i], *(const float4*)(hour_emb + i * DD + col))
    } else if (w == 2) {
#pragma unroll
      for (int i = 0; i < 8; ++i)
        FMA4(a0, whd[0][26 + i], *(const float4*)(day_emb + i * DD + col))
      const float4 s4 = *(const float4*)(src + row0 * DD + col);
      ADD4(a0, s4)
    } else if (w == 3) {
#pragma unroll
      for (int i = 0; i < 8; ++i)
        FMA4(a1, whd[1][26 + i], *(const float4*)(day_emb + i * DD + col))
      const float4 s4 = *(const float4*)(src + (row0 + 1) * DD + col);
      ADD4(a1, s4)
    }
    *(float4*)&ps[w][0][col] = a0;
    *(float4*)&ps[w][1][col] = a1;
  }
  __syncthreads();   // B6
  if (w < 2) {   // combine + LN1 (wave w = row w)
    float4 x = *(const float4*)&ps[0][w][col];
#pragma unroll
    for (int i = 1; i < 8; ++i) ADD4(x, (*(const float4*)&ps[i][w][col]))
    const float sm = wredSum(x.x + x.y + x.z + x.w);
    const float sq = wredSum(x.x*x.x + x.y*x.y + x.z*x.z + x.w*x.w);
    const float mean = sm * (1.f / DD);
    const float rstd = rsqrtf(sq * (1.f / DD) - mean * mean + 1e-5f);
    const float4 g4 = *(const float4*)(g11 + col);
    const float4 b4 = *(const float4*)(b11 + col);
    x.x = (x.x - mean) * rstd * g4.x + b4.x;
    x.y = (x.y - mean) * rstd * g4.y + b4.y;
    x.z = (x.z - mean) * rstd * g4.z + b4.z;
    x.w = (x.w - mean) * rstd * g4.w + b4.w;
    *(float4*)&xs2[w][col] = x;
  }
  __syncthreads();   // B7
  // ---- Phase 2: FFN1 e-slice (32 e's per wave), both rows per weight ----
  {
    float4 a0 = {0.f,0.f,0.f,0.f}, a1 = {0.f,0.f,0.f,0.f};
    const int e0 = 32 * w;
#pragma unroll 8
    for (int ee = 0; ee < 32; ++ee) {
      const int e = e0 + ee;
      const float4 w4 = *(const float4*)(wt1 + e * DD + col);
      FMA4(a0, xs2[0][e], w4)
      FMA4(a1, xs2[1][e], w4)
    }
    *(float4*)&ps[w][0][col] = a0;
    *(float4*)&ps[w][1][col] = a1;
  }
  __syncthreads();   // B8
  if (w < 2) {   // combine + bias + relu
    float4 h = *(const float4*)(bf1 + col);
#pragma unroll
    for (int i = 0; i < 8; ++i) ADD4(h, (*(const float4*)&ps[i][w][col]))
    h.x = fmaxf(h.x, 0.f); h.y = fmaxf(h.y, 0.f);
    h.z = fmaxf(h.z, 0.f); h.w = fmaxf(h.w, 0.f);
    *(float4*)&hs2[w][col] = h;
  }
  __syncthreads();   // B9
  // ---- Phase 3: FFN2 e-slice ----
  {
    float4 a0 = {0.f,0.f,0.f,0.f}, a1 = {0.f,0.f,0.f,0.f};
    const int e0 = 32 * w;
#pragma unroll 8
    for (int ee = 0; ee < 32; ++ee) {
      const int e = e0 + ee;
      const float4 w4 = *(const float4*)(wt2 + e * DD + col);
      FMA4(a0, hs2[0][e], w4)
      FMA4(a1, hs2[1][e], w4)
    }
    *(float4*)&ps[w][0][col] = a0;
    *(float4*)&ps[w][1][col] = a1;
  }
  __syncthreads();   // B10
  if (w < 2) {   // combine + bias + residual + LN2 + store
    float4 o = *(const float4*)(bf2 + col);
#pragma unroll
    for (int i = 0; i < 8; ++i) ADD4(o, (*(const float4*)&ps[i][w][col]))
    const float4 xr = *(const float4*)&xs2[w][col];
    ADD4(o, xr)
    const float sm = wredSum(o.x + o.y + o.z + o.w);
    const float sq = wredSum(o.x*o.x + o.y*o.y + o.z*o.z + o.w*o.w);
    const float mean = sm * (1.f / DD);
    const float rstd = rsqrtf(sq * (1.f / DD) - mean * mean + 1e-5f);
    const float4 g4 = *(const float4*)(g12 + col);
    const float4 b4 = *(const float4*)(b12 + col);
    o.x = (o.x - mean) * rstd * g4.x + b4.x;
    o.y = (o.y - mean) * rstd * g4.y + b4.y;
    o.z = (o.z - mean) * rstd * g4.z + b4.z;
    o.w = (o.w - mean) * rstd * g4.w + b4.w;
    *(float4*)(F + (row0 + w) * DD + col) = o;
  }
}

// ---------------------------------------------------------------------------
// Kernel 3: FUSED prep + decoder GEMM. grid (2 col-tiles of 512, 64 row-tiles
// of 8), 512 thr. Phase A: GS rows in LDS — histogram over 1024 (j,k) pairs,
// prefix split across two 256-thread groups (serial depth halved).
// Phase B: 512-col GEMM vs WTdec (1KB coalesced lines shared by 8 rows).
// ---------------------------------------------------------------------------
__global__ __launch_bounds__(512) void k_decf(
    const float* __restrict__ F,
    const float* __restrict__ hour_emb, const float* __restrict__ day_emb,
    const int* __restrict__ seq_lens, const int* __restrict__ ts_g,
    const int* __restrict__ lts_g,
    const float* __restrict__ wtd, const float* __restrict__ bdec,
    float* __restrict__ out)
{
  const int c0 = blockIdx.x * 512;
  const int r0g = blockIdx.y * 8;
  const int b = r0g >> 7, j0 = r0g & 127;
  const int t = threadIdx.x;
  __shared__ float xs[8][DD];
  __shared__ float cnt[8][34];
  __shared__ float pa[2][DD];
  for (int i = t; i < 8 * 34; i += 512) (&cnt[0][0])[i] = 0.f;
  __syncthreads();
  const int len = seq_lens[b];
  const int* ts = ts_g + b * LL;
  const int* lts = lts_g + b * LL;
#pragma unroll
  for (int p = 0; p < 2; ++p) {
    const int idx = p * 512 + t;
    const int jj = idx >> 7, k = idx & 127, j = j0 + jj;
    if (k <= j && j < len) {           // valid; no j==b override for labels
      const int ld = lts[j] - ts[k];   // >= 0
      atomicAdd(&cnt[jj][(ld % TU_C) / TB_C + 2], 1.f);
      atomicAdd(&cnt[jj][26 + min(ld / TU_C + 1, 7)], 1.f);
    }
  }
  // split prefix: group g covers k in [g*j0/2, (g+1)*j0/2); j0/2 mult of 4
  {
    const int g = t >> 8, d = t & 255;
    const int kb = (j0 >> 1) * g, ke = (j0 >> 1) * (g + 1);
    const float* fb = F + b * LL * DD + d;
    float A0 = 0.f, A1 = 0.f, A2 = 0.f, A3 = 0.f;
    for (int k = kb; k + 4 <= ke; k += 4) {
      A0 += fb[(k + 0) * DD]; A1 += fb[(k + 1) * DD];
      A2 += fb[(k + 2) * DD]; A3 += fb[(k + 3) * DD];
    }
    pa[g][d] = (A0 + A1) + (A2 + A3);
  }
  __syncthreads();
  if (t < 256) {
    float he[26], de[8];
#pragma unroll
    for (int i = 0; i < 26; ++i) he[i] = hour_emb[i * DD + t];
#pragma unroll
    for (int i = 0; i < 8; ++i)  de[i] = day_emb[i * DD + t];
    const float* fb = F + b * LL * DD + t;
    float gacc = pa[0][t] + pa[1][t];
#pragma unroll
    for (int jj = 0; jj < 8; ++jj) {
      gacc += fb[(j0 + jj) * DD];       // pooling sums ALL k<=j
      float s0 = 0.f, s1 = 0.f;
#pragma unroll
      for (int i = 0; i < 26; i += 2) {
        s0 += cnt[jj][i] * he[i]; s1 += cnt[jj][i + 1] * he[i + 1];
      }
#pragma unroll
      for (int i = 0; i < 8; i += 2) {
        s0 += cnt[jj][26 + i] * de[i]; s1 += cnt[jj][27 + i] * de[i + 1];
      }
      xs[jj][t] = (gacc + s0 + s1) / (float)(j0 + jj + 1);
    }
  }
  __syncthreads();
  const int cg = t & 127, rg = t >> 7;
  const int col = c0 + 4 * cg, rA = 2 * rg, rB = rA + 1;
  const float4 b4 = *(const float4*)(bdec + col);
  float4 a0 = b4, a1 = b4;
#pragma unroll 8
  for (int e = 0; e < DD; ++e) {
    const float4 w4 = *(const float4*)(wtd + e * PP + col);
    FMA4(a0, xs[rA][e], w4)
    FMA4(a1, xs[rB][e], w4)
  }
  *(float4*)(out + (r0g + rA) * PP + col) = a0;
  *(float4*)(out + (r0g + rB) * PP + col) = a1;
}

extern "C" void kernel_launch(void* const* d_in, const int* in_sizes, int n_in,
                              void* d_out, int out_size, void* d_ws, size_t ws_size,
                              hipStream_t stream)
{
  (void)in_sizes; (void)n_in; (void)out_size; (void)ws_size;
  const float* src      = (const float*)d_in[0];
  const float* hour_emb = (const float*)d_in[1];
  const float* day_emb  = (const float*)d_in[2];
  const float* wq  = (const float*)d_in[3];
  const float* bq  = (const float*)d_in[4];
  const float* wk  = (const float*)d_in[5];
  const float* bk  = (const float*)d_in[6];
  const float* wv  = (const float*)d_in[7];
  const float* bv  = (const float*)d_in[8];
  const float* g11 = (const float*)d_in[9];
  const float* b11 = (const float*)d_in[10];
  const float* wf1 = (const float*)d_in[11];
  const float* bf1 = (const float*)d_in[12];
  const float* wf2 = (const float*)d_in[13];
  const float* bf2 = (const float*)d_in[14];
  const float* g12 = (const float*)d_in[15];
  const float* b12 = (const float*)d_in[16];
  const float* wdec = (const float*)d_in[17];
  const float* bdec = (const float*)d_in[18];
  const int* seq_lens = (const int*)d_in[19];
  const int* ts  = (const int*)d_in[20];
  const int* lts = (const int*)d_in[21];
  float* out = (float*)d_out;
  float* ws = (float*)d_ws;
  // ws layout (floats):
  float* WT = ws;                  // 589824 (5x65536 + 262144)
  float* Q  = ws + 589824;         // 131072
  float* KT = ws + 720896;         // 131072 (4 x [256e][128k])
  float* V  = ws + 851968;         // 131072
  float* F  = ws + 983040;         // 131072

  k_wt  <<<576, 256, 0, stream>>>(wq, wk, wv, wf1, wf2, wdec, WT);
  k_qkv <<<dim3(64, 3), 512, 0, stream>>>(src, WT, bq, bk, bv, Q, KT, V);
  k_attn<<<256, 512, 0, stream>>>(Q, KT, V, src, hour_emb, day_emb, seq_lens, ts,
                                  g11, b11, WT + 196608, bf1, WT + 262144, bf2,
                                  g12, b12, F);
  k_decf<<<dim3(2, 64), 512, 0, stream>>>(F, hour_emb, day_emb, seq_lens, ts, lts,
                                          WT + 327680, bdec, out);
}

// Round 12
// 50.403 us; speedup vs baseline: 1.3958x; 1.3958x over previous
//
#include <hip/hip_runtime.h>
#include <hip/hip_bf16.h>

#define LL 128
#define DD 256
#define PP 1024
#define TU_C 86400
#define TB_C 3600
#define NEGF -4294967296.0f   // float(-2**32+1) rounds to -2^32

// NOTE: parameter names must not collide with .x/.y/.z/.w member tokens
#define FMA4(ACC_, SS_, WW_) { (ACC_).x += (SS_)*(WW_).x; (ACC_).y += (SS_)*(WW_).y; (ACC_).z += (SS_)*(WW_).z; (ACC_).w += (SS_)*(WW_).w; }
#define ADD4(ACC_, WW_) { (ACC_).x += (WW_).x; (ACC_).y += (WW_).y; (ACC_).z += (WW_).z; (ACC_).w += (WW_).w; }

__device__ __forceinline__ float wredSum(float v) {
#pragma unroll
  for (int o = 32; o; o >>= 1) v += __shfl_xor(v, o);
  return v;
}
__device__ __forceinline__ float wredMax(float v) {
#pragma unroll
  for (int o = 32; o; o >>= 1) v = fmaxf(v, __shfl_xor(v, o));
  return v;
}

// ---------------------------------------------------------------------------
// Kernel 0: transpose weights. WT: WTq 0, WTk 65536, WTv 131072, WTf1 196608,
// WTf2 262144, WTdec 327680. 32x32 tiles, 576 blocks. (proven)
// ---------------------------------------------------------------------------
__global__ __launch_bounds__(256) void k_wt(
    const float* __restrict__ wq, const float* __restrict__ wk,
    const float* __restrict__ wv, const float* __restrict__ wf1,
    const float* __restrict__ wf2, const float* __restrict__ wdec,
    float* __restrict__ wt)
{
  __shared__ float s[32][33];
  const int tile = blockIdx.x;
  const float* src; float* dst; int R, m;
  if (tile < 320) {
    const int mi = tile >> 6; m = tile & 63;
    src = (mi == 0) ? wq : (mi == 1) ? wk : (mi == 2) ? wv : (mi == 3) ? wf1 : wf2;
    dst = wt + mi * 65536; R = 256;
  } else {
    m = tile - 320; src = wdec; dst = wt + 327680; R = 1024;
  }
  const int sr = (m >> 3) * 32, sc0 = (m & 7) * 32;
  const int tx = threadIdx.x & 31, ty = threadIdx.x >> 5;
#pragma unroll
  for (int i = 0; i < 4; ++i)
    s[ty + 8 * i][tx] = src[(sr + ty + 8 * i) * 256 + sc0 + tx];
  __syncthreads();
#pragma unroll
  for (int i = 0; i < 4; ++i)
    dst[(sc0 + ty + 8 * i) * R + sr + tx] = s[tx][ty + 8 * i];
}

// ---------------------------------------------------------------------------
// Kernel 1: Q/K/V projections. grid (64,3), 256 thr = 4 waves.
// Wave w owns e-slice [64w,64w+64): each weight element loaded ONCE per
// block; 8 rows per thread via LDS broadcast; LDS combine.
// K written TRANSPOSED per batch: KT[b][e][k].
// ---------------------------------------------------------------------------
__global__ __launch_bounds__(256) void k_qkv(
    const float* __restrict__ src, const float* __restrict__ wt,
    const float* __restrict__ bq, const float* __restrict__ bk,
    const float* __restrict__ bv,
    float* __restrict__ Q, float* __restrict__ KT, float* __restrict__ V)
{
  __shared__ float xs[8][DD];
  __shared__ float ps[4][8][DD];
  const int t = threadIdx.x, l = t & 63, w = t >> 6;
  const int r0 = blockIdx.x * 8;
  const int mat = blockIdx.y;
  const float* wm = wt + mat * 65536;
  for (int i = t; i < 8 * DD; i += 256) xs[i >> 8][i & 255] = src[r0 * DD + i];
  __syncthreads();
  const int col = 4 * l;
  float4 acc[8];
#pragma unroll
  for (int r = 0; r < 8; ++r) acc[r] = (float4){0.f, 0.f, 0.f, 0.f};
  const int e0 = 64 * w;
  for (int e = e0; e < e0 + 64; e += 4) {
    float4 xr[8];
#pragma unroll
    for (int r = 0; r < 8; ++r) xr[r] = *(const float4*)&xs[r][e];
#pragma unroll
    for (int c = 0; c < 4; ++c) {
      const float4 w4 = *(const float4*)(wm + (e + c) * DD + col);
#pragma unroll
      for (int r = 0; r < 8; ++r) {
        const float xv = (c == 0) ? xr[r].x : (c == 1) ? xr[r].y : (c == 2) ? xr[r].z : xr[r].w;
        FMA4(acc[r], xv, w4)
      }
    }
  }
#pragma unroll
  for (int r = 0; r < 8; ++r) *(float4*)&ps[w][r][col] = acc[r];
  __syncthreads();
  const float* bi = (mat == 0) ? bq : (mat == 1) ? bk : bv;
#pragma unroll
  for (int g = 0; g < 2; ++g) {
    const int combo = g * 256 + t;
    const int r = combo >> 6, cgp = combo & 63;
    const int c4 = 4 * cgp;
    float4 o = *(const float4*)(bi + c4);
    ADD4(o, (*(const float4*)&ps[0][r][c4]))
    ADD4(o, (*(const float4*)&ps[1][r][c4]))
    ADD4(o, (*(const float4*)&ps[2][r][c4]))
    ADD4(o, (*(const float4*)&ps[3][r][c4]))
    const int rr = r0 + r;
    if (mat == 1) {
      const int bA = rr >> 7, kA = rr & 127;
      KT[bA * 32768 + (c4 + 0) * 128 + kA] = o.x;
      KT[bA * 32768 + (c4 + 1) * 128 + kA] = o.y;
      KT[bA * 32768 + (c4 + 2) * 128 + kA] = o.z;
      KT[bA * 32768 + (c4 + 3) * 128 + kA] = o.w;
    } else {
      float* op = (mat == 0) ? Q : V;
      *(float4*)(op + rr * DD + c4) = o;
    }
  }
}

// ---------------------------------------------------------------------------
// Kernel 2: FULLY FUSED attention + FFN. grid 256 = (b, 64 row-pairs),
// 512 thr = 8 waves. (round-11 structure, proven correct)
// ---------------------------------------------------------------------------
__global__ __launch_bounds__(512) void k_attn(
    const float* __restrict__ Q, const float* __restrict__ KT,
    const float* __restrict__ Vm, const float* __restrict__ src,
    const float* __restrict__ hour_emb, const float* __restrict__ day_emb,
    const int* __restrict__ seq_lens, const int* __restrict__ ts_g,
    const float* __restrict__ g11, const float* __restrict__ b11,
    const float* __restrict__ wt1, const float* __restrict__ bf1,
    const float* __restrict__ wt2, const float* __restrict__ bf2,
    const float* __restrict__ g12, const float* __restrict__ b12,
    float* __restrict__ F)
{
  const int b = blockIdx.x >> 6;
  const int j0 = (blockIdx.x & 63) * 2;
  const int t = threadIdx.x, w = t >> 6, l = t & 63;
  const int col = 4 * l;
  __shared__ float qs[2][DD];
  __shared__ int   tsl[LL];
  __shared__ float qhd[2][34];
  __shared__ float whd[2][34];
  __shared__ float red[8];
  __shared__ float ss[2][LL];
  __shared__ float xs2[2][DD];
  __shared__ float hs2[2][DD];
  __shared__ float ps[8][2][DD];
  const int row0 = b * LL + j0;
  qs[t >> 8][t & 255] = Q[row0 * DD + t];    // 512 threads = 2x256
  if (t < LL) tsl[t] = ts_g[b * LL + t];
  if (t < 68) whd[t / 34][t % 34] = 0.f;
  __syncthreads();   // B1
  // ---- K-dots (waves 0-3) and emb dots (waves 4-5) in parallel ----
  float kdot = 0.f;
  int krow = 0, kidx = 0;
  if (w < 4) {
    krow = w >> 1;
    kidx = ((w & 1) << 6) | l;
    const float* ktb = KT + b * 32768;
    float4 kd = {0.f,0.f,0.f,0.f};
#pragma unroll 8
    for (int e = 0; e < DD; e += 4) {
      const float4 q4 = *(const float4*)&qs[krow][e];
      const float* kp = ktb + e * LL + kidx;
      kd.x += q4.x * kp[0];
      kd.y += q4.y * kp[128];
      kd.z += q4.z * kp[256];
      kd.w += q4.w * kp[384];
    }
    kdot = (kd.x + kd.y) + (kd.z + kd.w);
  } else if (w < 6 && l < 34) {
    const int r = w - 4;
    const float* ep = (l < 26) ? (hour_emb + l * DD) : (day_emb + (l - 26) * DD);
    float4 ed = {0.f,0.f,0.f,0.f};
    for (int e = 0; e < DD; e += 4) {
      const float4 q4 = *(const float4*)&qs[r][e];
      const float4 e4 = *(const float4*)(ep + e);
      ed.x += q4.x * e4.x; ed.y += q4.y * e4.y;
      ed.z += q4.z * e4.z; ed.w += q4.w * e4.w;
    }
    qhd[r][l] = (ed.x + ed.y) + (ed.z + ed.w);
  }
  __syncthreads();   // B2 (qhd ready)
  // ---- scores + cross-wave softmax ----
  const int len = seq_lens[b];
  float s = NEGF;
  int hidx = 0, didx = 0;
  if (w < 4) {
    const int jrow = j0 + krow;
    if (kidx <= jrow && jrow < len) {
      const int df = tsl[jrow] - tsl[kidx];              // >=0 (sorted, k<=j)
      hidx = (jrow == b) ? 1 : ((df % TU_C) / TB_C + 2); // faithful j==b bug
      didx = min(df / TU_C + 1, 7);
      s = (kdot + qhd[krow][hidx] + qhd[krow][26 + didx]) * 0.0625f;
    }
    const float mv = wredMax(s);
    if (l == 0) red[w] = mv;
  }
  __syncthreads();   // B3
  float p = 0.f;
  if (w < 4) {
    const float m = fmaxf(red[2 * krow], red[2 * krow + 1]);
    p = expf(s - m);                 // all-NEG row -> p=1 everywhere
    const float sv = wredSum(p);
    if (l == 0) red[4 + w] = sv;
  }
  __syncthreads();   // B4
  if (w < 4) {
    const float Z = red[4 + 2 * krow] + red[5 + 2 * krow];
    const float aw = p / Z;          // all-NEG row -> uniform 1/128
    ss[krow][kidx] = aw;
    atomicAdd(&whd[krow][hidx], aw);       // idx 0 -> zero emb row: harmless
    atomicAdd(&whd[krow][26 + didx], aw);
  }
  __syncthreads();   // B5
  // ---- Phase 1: aw@V k-slice (16 k's per wave), both rows ----
  {
    float4 a0 = {0.f,0.f,0.f,0.f}, a1 = {0.f,0.f,0.f,0.f};
    const float* vb = Vm + b * LL * DD + col;
    const int k0 = 16 * w;
#pragma unroll
    for (int kk = 0; kk < 16; ++kk) {
      const int k = k0 + kk;
      const float4 v4 = *(const float4*)(vb + k * DD);
      FMA4(a0, ss[0][k], v4)
      FMA4(a1, ss[1][k], v4)
    }
    if (w == 0) {
#pragma unroll
      for (int i = 0; i < 26; ++i)
        FMA4(a0, whd[0][i], *(const float4*)(hour_emb + i * DD + col))
    } else if (w == 1) {
#pragma unroll
      for (int i = 0; i < 26; ++i)
        FMA4(a1, whd[1][i], *(const float4*)(hour_emb + i * DD + col))
    } else if (w == 2) {
#pragma unroll
      for (int i = 0; i < 8; ++i)
        FMA4(a0, whd[0][26 + i], *(const float4*)(day_emb + i * DD + col))
      const float4 s4 = *(const float4*)(src + row0 * DD + col);
      ADD4(a0, s4)
    } else if (w == 3) {
#pragma unroll
      for (int i = 0; i < 8; ++i)
        FMA4(a1, whd[1][26 + i], *(const float4*)(day_emb + i * DD + col))
      const float4 s4 = *(const float4*)(src + (row0 + 1) * DD + col);
      ADD4(a1, s4)
    }
    *(float4*)&ps[w][0][col] = a0;
    *(float4*)&ps[w][1][col] = a1;
  }
  __syncthreads();   // B6
  if (w < 2) {   // combine + LN1 (wave w = row w)
    float4 x = *(const float4*)&ps[0][w][col];
#pragma unroll
    for (int i = 1; i < 8; ++i) ADD4(x, (*(const float4*)&ps[i][w][col]))
    const float sm = wredSum(x.x + x.y + x.z + x.w);
    const float sq = wredSum(x.x*x.x + x.y*x.y + x.z*x.z + x.w*x.w);
    const float mean = sm * (1.f / DD);
    const float rstd = rsqrtf(sq * (1.f / DD) - mean * mean + 1e-5f);
    const float4 g4 = *(const float4*)(g11 + col);
    const float4 b4 = *(const float4*)(b11 + col);
    x.x = (x.x - mean) * rstd * g4.x + b4.x;
    x.y = (x.y - mean) * rstd * g4.y + b4.y;
    x.z = (x.z - mean) * rstd * g4.z + b4.z;
    x.w = (x.w - mean) * rstd * g4.w + b4.w;
    *(float4*)&xs2[w][col] = x;
  }
  __syncthreads();   // B7
  // ---- Phase 2: FFN1 e-slice (32 e's per wave), both rows per weight ----
  {
    float4 a0 = {0.f,0.f,0.f,0.f}, a1 = {0.f,0.f,0.f,0.f};
    const int e0 = 32 * w;
#pragma unroll 8
    for (int ee = 0; ee < 32; ++ee) {
      const int e = e0 + ee;
      const float4 w4 = *(const float4*)(wt1 + e * DD + col);
      FMA4(a0, xs2[0][e], w4)
      FMA4(a1, xs2[1][e], w4)
    }
    *(float4*)&ps[w][0][col] = a0;
    *(float4*)&ps[w][1][col] = a1;
  }
  __syncthreads();   // B8
  if (w < 2) {   // combine + bias + relu
    float4 h = *(const float4*)(bf1 + col);
#pragma unroll
    for (int i = 0; i < 8; ++i) ADD4(h, (*(const float4*)&ps[i][w][col]))
    h.x = fmaxf(h.x, 0.f); h.y = fmaxf(h.y, 0.f);
    h.z = fmaxf(h.z, 0.f); h.w = fmaxf(h.w, 0.f);
    *(float4*)&hs2[w][col] = h;
  }
  __syncthreads();   // B9
  // ---- Phase 3: FFN2 e-slice ----
  {
    float4 a0 = {0.f,0.f,0.f,0.f}, a1 = {0.f,0.f,0.f,0.f};
    const int e0 = 32 * w;
#pragma unroll 8
    for (int ee = 0; ee < 32; ++ee) {
      const int e = e0 + ee;
      const float4 w4 = *(const float4*)(wt2 + e * DD + col);
      FMA4(a0, hs2[0][e], w4)
      FMA4(a1, hs2[1][e], w4)
    }
    *(float4*)&ps[w][0][col] = a0;
    *(float4*)&ps[w][1][col] = a1;
  }
  __syncthreads();   // B10
  if (w < 2) {   // combine + bias + residual + LN2 + store
    float4 o = *(const float4*)(bf2 + col);
#pragma unroll
    for (int i = 0; i < 8; ++i) ADD4(o, (*(const float4*)&ps[i][w][col]))
    const float4 xr = *(const float4*)&xs2[w][col];
    ADD4(o, xr)
    const float sm = wredSum(o.x + o.y + o.z + o.w);
    const float sq = wredSum(o.x*o.x + o.y*o.y + o.z*o.z + o.w*o.w);
    const float mean = sm * (1.f / DD);
    const float rstd = rsqrtf(sq * (1.f / DD) - mean * mean + 1e-5f);
    const float4 g4 = *(const float4*)(g12 + col);
    const float4 b4 = *(const float4*)(b12 + col);
    o.x = (o.x - mean) * rstd * g4.x + b4.x;
    o.y = (o.y - mean) * rstd * g4.y + b4.y;
    o.z = (o.z - mean) * rstd * g4.z + b4.z;
    o.w = (o.w - mean) * rstd * g4.w + b4.w;
    *(float4*)(F + (row0 + w) * DD + col) = o;
  }
}

// ---------------------------------------------------------------------------
// Kernel 3: FUSED prep + decoder GEMM. grid (4 col-tiles of 256, 64 row-tiles
// of 8) = 256 blocks, 256 thr = 4 waves.
// Phase A: GS rows in LDS (histogram + prefix over F + label-emb).
// Phase B: split-e GEMM — wave w owns e-slice [64w,64w+64); each wtd element
// loaded ONCE per block; 8 rows/thread via LDS broadcast; LDS combine.
// ---------------------------------------------------------------------------
__global__ __launch_bounds__(256) void k_decf(
    const float* __restrict__ F,
    const float* __restrict__ hour_emb, const float* __restrict__ day_emb,
    const int* __restrict__ seq_lens, const int* __restrict__ ts_g,
    const int* __restrict__ lts_g,
    const float* __restrict__ wtd, const float* __restrict__ bdec,
    float* __restrict__ out)
{
  const int c0 = blockIdx.x * 256;
  const int r0g = blockIdx.y * 8;
  const int b = r0g >> 7, j0 = r0g & 127;
  const int t = threadIdx.x, l = t & 63, w = t >> 6;
  __shared__ float xs[8][DD];
  __shared__ float cnt[8][34];
  __shared__ float ps[4][8][DD];
  for (int i = t; i < 8 * 34; i += 256) (&cnt[0][0])[i] = 0.f;
  __syncthreads();
  const int len = seq_lens[b];
  const int* ts = ts_g + b * LL;
  const int* lts = lts_g + b * LL;
#pragma unroll
  for (int p = 0; p < 4; ++p) {
    const int idx = p * 256 + t;
    const int jj = idx >> 7, k = idx & 127, j = j0 + jj;
    if (k <= j && j < len) {           // valid; no j==b override for labels
      const int ld = lts[j] - ts[k];   // >= 0
      atomicAdd(&cnt[jj][(ld % TU_C) / TB_C + 2], 1.f);
      atomicAdd(&cnt[jj][26 + min(ld / TU_C + 1, 7)], 1.f);
    }
  }
  __syncthreads();
  {
    float he[26], de[8];
#pragma unroll
    for (int i = 0; i < 26; ++i) he[i] = hour_emb[i * DD + t];
#pragma unroll
    for (int i = 0; i < 8; ++i)  de[i] = day_emb[i * DD + t];
    const float* fb = F + b * LL * DD + t;
    float A0 = 0.f, A1 = 0.f, A2 = 0.f, A3 = 0.f;
#pragma unroll 4
    for (int k = 0; k < j0; k += 4) {   // j0 multiple of 8
      A0 += fb[(k + 0) * DD]; A1 += fb[(k + 1) * DD];
      A2 += fb[(k + 2) * DD]; A3 += fb[(k + 3) * DD];
    }
    float gacc = (A0 + A1) + (A2 + A3);
#pragma unroll
    for (int jj = 0; jj < 8; ++jj) {
      gacc += fb[(j0 + jj) * DD];       // pooling sums ALL k<=j
      float s0 = 0.f, s1 = 0.f;
#pragma unroll
      for (int i = 0; i < 26; i += 2) {
        s0 += cnt[jj][i] * he[i]; s1 += cnt[jj][i + 1] * he[i + 1];
      }
#pragma unroll
      for (int i = 0; i < 8; i += 2) {
        s0 += cnt[jj][26 + i] * de[i]; s1 += cnt[jj][27 + i] * de[i + 1];
      }
      xs[jj][t] = (gacc + s0 + s1) / (float)(j0 + jj + 1);
    }
  }
  __syncthreads();
  // ---- Phase B: split-e GEMM ----
  const int col = c0 + 4 * l;
  float4 acc[8];
#pragma unroll
  for (int r = 0; r < 8; ++r) acc[r] = (float4){0.f, 0.f, 0.f, 0.f};
  const int e0 = 64 * w;
  for (int e = e0; e < e0 + 64; e += 4) {
    float4 xr[8];
#pragma unroll
    for (int r = 0; r < 8; ++r) xr[r] = *(const float4*)&xs[r][e];
#pragma unroll
    for (int c = 0; c < 4; ++c) {
      const float4 w4 = *(const float4*)(wtd + (e + c) * PP + col);
#pragma unroll
      for (int r = 0; r < 8; ++r) {
        const float xv = (c == 0) ? xr[r].x : (c == 1) ? xr[r].y : (c == 2) ? xr[r].z : xr[r].w;
        FMA4(acc[r], xv, w4)
      }
    }
  }
#pragma unroll
  for (int r = 0; r < 8; ++r) *(float4*)&ps[w][r][4 * l] = acc[r];
  __syncthreads();
#pragma unroll
  for (int g = 0; g < 2; ++g) {
    const int combo = g * 256 + t;
    const int r = combo >> 6, cgp = combo & 63;
    const int c4 = 4 * cgp;
    float4 o = *(const float4*)(bdec + c0 + c4);
    ADD4(o, (*(const float4*)&ps[0][r][c4]))
    ADD4(o, (*(const float4*)&ps[1][r][c4]))
    ADD4(o, (*(const float4*)&ps[2][r][c4]))
    ADD4(o, (*(const float4*)&ps[3][r][c4]))
    *(float4*)(out + (r0g + r) * PP + c0 + c4) = o;
  }
}

extern "C" void kernel_launch(void* const* d_in, const int* in_sizes, int n_in,
                              void* d_out, int out_size, void* d_ws, size_t ws_size,
                              hipStream_t stream)
{
  (void)in_sizes; (void)n_in; (void)out_size; (void)ws_size;
  const float* src      = (const float*)d_in[0];
  const float* hour_emb = (const float*)d_in[1];
  const float* day_emb  = (const float*)d_in[2];
  const float* wq  = (const float*)d_in[3];
  const float* bq  = (const float*)d_in[4];
  const float* wk  = (const float*)d_in[5];
  const float* bk  = (const float*)d_in[6];
  const float* wv  = (const float*)d_in[7];
  const float* bv  = (const float*)d_in[8];
  const float* g11 = (const float*)d_in[9];
  const float* b11 = (const float*)d_in[10];
  const float* wf1 = (const float*)d_in[11];
  const float* bf1 = (const float*)d_in[12];
  const float* wf2 = (const float*)d_in[13];
  const float* bf2 = (const float*)d_in[14];
  const float* g12 = (const float*)d_in[15];
  const float* b12 = (const float*)d_in[16];
  const float* wdec = (const float*)d_in[17];
  const float* bdec = (const float*)d_in[18];
  const int* seq_lens = (const int*)d_in[19];
  const int* ts  = (const int*)d_in[20];
  const int* lts = (const int*)d_in[21];
  float* out = (float*)d_out;
  float* ws = (float*)d_ws;
  // ws layout (floats):
  float* WT = ws;                  // 589824 (5x65536 + 262144)
  float* Q  = ws + 589824;         // 131072
  float* KT = ws + 720896;         // 131072 (4 x [256e][128k])
  float* V  = ws + 851968;         // 131072
  float* F  = ws + 983040;         // 131072

  k_wt  <<<576, 256, 0, stream>>>(wq, wk, wv, wf1, wf2, wdec, WT);
  k_qkv <<<dim3(64, 3), 256, 0, stream>>>(src, WT, bq, bk, bv, Q, KT, V);
  k_attn<<<256, 512, 0, stream>>>(Q, KT, V, src, hour_emb, day_emb, seq_lens, ts,
                                  g11, b11, WT + 196608, bf1, WT + 262144, bf2,
                                  g12, b12, F);
  k_decf<<<dim3(4, 64), 256, 0, stream>>>(F, hour_emb, day_emb, seq_lens, ts, lts,
                                          WT + 327680, bdec, out);
}